// Round 3
// baseline (142.827 us; speedup 1.0000x reference)
//
#include <hip/hip_runtime.h>
#include <hip/hip_bf16.h>

// Problem constants
#define BB 32
#define LL 2048
#define DD 64
#define TT 512
// H=2, P=2 -> hp index = h*2+p in [0,4)

// Workspace layout (in floats)
#define WS_R    0                       // r[hp][i] : 4*128 = 512
#define WS_C    512                     // c[hp] : 4
#define WS_ACC  576                     // per b: numer[4*64] denom[4*64] sumX[64] = 576
#define ACC_STRIDE 576
#define WS_A    (576 + 32*576)          // A[b][k] : 32*64
#define WS_B    (WS_A + 2048)           // B[b][k] : 32*64

// ---------------------------------------------------------------------------
// K1: q = query@qm_w + qm_b ; r[hp][i] = sum_e q[p][h*64+e]*km_w[i][h*64+e] ;
//     c[hp] = sum_e q[p][h*64+e]*km_b[h*64+e]. Also zeroes accumulators.
// ---------------------------------------------------------------------------
__global__ void __launch_bounds__(256) k1_prep(
    const float* __restrict__ query,
    const float* __restrict__ qm_w,
    const float* __restrict__ qm_b,
    const float* __restrict__ km_w,
    const float* __restrict__ km_b,
    float* __restrict__ ws) {
  __shared__ float q_lds[2 * 128];
  const int t = threadIdx.x;  // 256 threads

  // zero the atomic accumulators (harness poisons ws with 0xAA)
  for (int i = t; i < 32 * ACC_STRIDE; i += 256) ws[WS_ACC + i] = 0.f;

  {  // q[p][e]
    const int p = t >> 7, e = t & 127;
    float acc = qm_b[e];
    for (int i = 0; i < 128; ++i)
      acc += query[p * 128 + i] * qm_w[i * 128 + e];
    q_lds[p * 128 + e] = acc;
  }
  __syncthreads();

  for (int o = t; o < 512; o += 256) {  // r[hp][i]
    const int hp = o >> 7, i = o & 127;
    const int h = hp >> 1, p = hp & 1;
    float acc = 0.f;
    for (int e = 0; e < 64; ++e)
      acc += q_lds[p * 128 + h * 64 + e] * km_w[i * 128 + h * 64 + e];
    ws[WS_R + o] = acc;
  }
  if (t < 4) {  // c[hp]
    const int h = t >> 1, p = t & 1;
    float acc = 0.f;
    for (int e = 0; e < 64; ++e)
      acc += q_lds[p * 128 + h * 64 + e] * km_b[h * 64 + e];
    ws[WS_C + t] = acc;
  }
}

// ---------------------------------------------------------------------------
// K2: fused scores -> exp -> masked weighted sums over a 128-row L-chunk.
// grid (L/128=16, B=32), block 256.
//   w[l][hp] = exp( (sum_i f_i(t_l) * r[hp][i] + c[hp]) / 8 )
//   numer[hp][d] += w*M*X ; denom[hp][d] += w*M ; sumX[d] += X
// partials reduced in LDS then atomicAdd'd into ws accumulators.
// ---------------------------------------------------------------------------
__global__ void __launch_bounds__(256) k2_attn(
    const float* __restrict__ ts,
    const float* __restrict__ X,
    const float* __restrict__ M,
    const float* __restrict__ te_w,
    const float* __restrict__ te_b,
    float* __restrict__ ws) {
  __shared__ float tew[128], teb[128], r_lds[512], c_lds[4];
  __shared__ float w_lds[128 * 4];
  __shared__ float red[256 * 18];
  const int t = threadIdx.x;
  const int b = blockIdx.y;
  const int lc = blockIdx.x * 128;

  if (t < 128) { tew[t] = te_w[t]; teb[t] = te_b[t]; }
  r_lds[t] = ws[WS_R + t];
  r_lds[t + 256] = ws[WS_R + t + 256];
  if (t < 4) c_lds[t] = ws[WS_C + t];
  __syncthreads();

  {  // scores: 2 threads per l, each does 2 of the 4 hp dot-products
    const int ll = t >> 1, pair = t & 1;
    const float tt = ts[(size_t)b * LL + lc + ll];
    float a0 = 0.f, a1 = 0.f;
    const float* r0 = &r_lds[(pair * 2) * 128];
    const float* r1 = &r_lds[(pair * 2 + 1) * 128];
    for (int i = 0; i < 128; i += 2) {
      const float f0 = __sinf(tt * tew[i] + teb[i]);      // even idx: sin
      const float f1 = tt * tew[i + 1] + teb[i + 1];      // odd idx: identity
      a0 += f0 * r0[i] + f1 * r0[i + 1];
      a1 += f0 * r1[i] + f1 * r1[i + 1];
    }
    // scores are O(0.3): exp without max-subtraction is exact-safe and
    // softmax is shift-invariant, so this matches the reference.
    w_lds[ll * 4 + pair * 2]     = __expf((a0 + c_lds[pair * 2]) * 0.125f);
    w_lds[ll * 4 + pair * 2 + 1] = __expf((a1 + c_lds[pair * 2 + 1]) * 0.125f);
  }
  __syncthreads();

  // accumulate: thread -> (lr = t>>5 row group of 8, dpair = t&31 -> d=2*dpair)
  const int dpair = t & 31, lr = t >> 5;
  float n[4][2] = {}, dn[4][2] = {}, sx[2] = {};
  const float2* X2 = (const float2*)X;
  const float2* M2 = (const float2*)M;
  const size_t base = ((size_t)b * LL + lc) * 32;  // float2 units per row = 32
  for (int ll = lr; ll < 128; ll += 8) {
    const float2 xv = X2[base + (size_t)ll * 32 + dpair];
    const float2 mv = M2[base + (size_t)ll * 32 + dpair];
    const float mx0 = mv.x * xv.x, mx1 = mv.y * xv.y;
    sx[0] += xv.x; sx[1] += xv.y;
#pragma unroll
    for (int hp = 0; hp < 4; ++hp) {
      const float w = w_lds[ll * 4 + hp];
      n[hp][0]  += w * mx0;  n[hp][1]  += w * mx1;
      dn[hp][0] += w * mv.x; dn[hp][1] += w * mv.y;
    }
  }

#pragma unroll
  for (int hp = 0; hp < 4; ++hp) {
    red[t * 18 + hp * 2 + 0] = n[hp][0];
    red[t * 18 + hp * 2 + 1] = n[hp][1];
    red[t * 18 + 8 + hp * 2 + 0] = dn[hp][0];
    red[t * 18 + 8 + hp * 2 + 1] = dn[hp][1];
  }
  red[t * 18 + 16] = sx[0];
  red[t * 18 + 17] = sx[1];
  __syncthreads();

  if (t < 32) {
    float* accb = ws + WS_ACC + b * ACC_STRIDE;
    for (int j = 0; j < 18; ++j) {
      float s = 0.f;
#pragma unroll
      for (int r2 = 0; r2 < 8; ++r2) s += red[(r2 * 32 + t) * 18 + j];
      if (j < 8) {
        const int hp = j >> 1, half = j & 1;
        atomicAdd(&accb[hp * 64 + 2 * t + half], s);
      } else if (j < 16) {
        const int j2 = j - 8, hp = j2 >> 1, half = j2 & 1;
        atomicAdd(&accb[256 + hp * 64 + 2 * t + half], s);
      } else {
        atomicAdd(&accb[512 + 2 * t + (j - 16)], s);
      }
    }
  }
}

// ---------------------------------------------------------------------------
// K3: per-b finalize. x = numer/denom (second half of value == mask -> x==1),
// coeffs = xflat @ out_w + out_b (written to output as fp32), then
// A[k] = dec_b1[k] + sum_j c0[j]*w1[j][k], B[k] = sum_j c1[j]*w1[j][k].
// grid 32 blocks x 128 threads.
// ---------------------------------------------------------------------------
__global__ void __launch_bounds__(128) k3_coeffs(
    const float* __restrict__ out_w,
    const float* __restrict__ out_b,
    const float* __restrict__ dec_w1,
    const float* __restrict__ dec_b1,
    float* __restrict__ ws,
    float* __restrict__ out) {
  __shared__ float x_lds[2 * 256];  // [p][h*128 + dd]
  __shared__ float c_lds[2 * 64];
  const int t = threadIdx.x;  // 128
  const int b = blockIdx.x;
  const float* accb = ws + WS_ACC + b * ACC_STRIDE;

  for (int o = t; o < 256; o += 128) {
    const int hp = o >> 6, d = o & 63;
    const int h = hp >> 1, p = hp & 1;
    const float num = accb[hp * 64 + d];
    const float den = accb[256 + hp * 64 + d];
    const float sxv = accb[512 + d];
    float x1, x2;
    if (den > 0.f) { x1 = num / den; x2 = 1.f; }
    else           { x1 = sxv * (1.f / (float)LL); x2 = 0.f; }  // uniform fallback
    x_lds[p * 256 + h * 128 + d] = x1;
    x_lds[p * 256 + h * 128 + 64 + d] = x2;
  }
  __syncthreads();

  {  // coeffs[b][p][j]
    const int p = t >> 6, j = t & 63;
    float acc = out_b[j];
    for (int k = 0; k < 256; ++k)
      acc += x_lds[p * 256 + k] * out_w[k * 64 + j];
    out[(size_t)BB * TT * DD + b * 128 + p * 64 + j] = acc;  // fp32 coeffs
    c_lds[p * 64 + j] = acc;
  }
  __syncthreads();

  if (t < 64) {
    const int k = t;
    float a = dec_b1[k], bb = 0.f;
    for (int j = 0; j < 64; ++j) {
      const float w1 = dec_w1[j * 64 + k];
      a  += c_lds[j] * w1;
      bb += c_lds[64 + j] * w1;
    }
    ws[WS_A + b * 64 + k] = a;
    ws[WS_B + b * 64 + k] = bb;
  }
}

// ---------------------------------------------------------------------------
// K4: decoder. h1[t][k] = relu(A[k] + y_t*B[k]);
// out[t][d] = dec_b2[d] + sum_k h1[t][k]*w2[k][d].  fp32 output.
// grid (T/64=8, B=32), block 256. Each block: 64 t's in 4 groups of 16.
// ---------------------------------------------------------------------------
__global__ void __launch_bounds__(256) k4_decode(
    const float* __restrict__ yts,
    const float* __restrict__ dec_w2,
    const float* __restrict__ dec_b2,
    const float* __restrict__ ws,
    float* __restrict__ out) {
  __shared__ __align__(16) float w2l[4096];  // [k*64 + d] fp32
  __shared__ float h1l[16 * 64];
  __shared__ float Al[64], Bl[64], b2l[64], yl[64];
  const int t = threadIdx.x;
  const int b = blockIdx.y;
  const int t0 = blockIdx.x * 64;

  for (int i = t; i < 4096; i += 256) w2l[i] = dec_w2[i];
  if (t < 64) {
    Al[t]  = ws[WS_A + b * 64 + t];
    Bl[t]  = ws[WS_B + b * 64 + t];
    b2l[t] = dec_b2[t];
    yl[t]  = yts[(size_t)b * TT + t0 + t];
  }
  __syncthreads();

  const int tl = t >> 4, dg = t & 15;  // 16 t's x 16 d-groups(4 d each)
  for (int it = 0; it < 4; ++it) {
    {  // phase A: h1 for 16 t's (1024 values, 4 per thread)
      int idx = t;
#pragma unroll
      for (int rr = 0; rr < 4; ++rr, idx += 256) {
        const int tl2 = idx >> 6, k = idx & 63;
        h1l[idx] = fmaxf(Al[k] + yl[it * 16 + tl2] * Bl[k], 0.f);
      }
    }
    __syncthreads();
    {  // phase B: out tile
      float a0 = b2l[dg * 4], a1 = b2l[dg * 4 + 1],
            a2 = b2l[dg * 4 + 2], a3 = b2l[dg * 4 + 3];
      const float4* w4 = (const float4*)w2l;
      const float* h1p = &h1l[tl * 64];
      for (int k = 0; k < 64; ++k) {
        const float h = h1p[k];
        const float4 w = w4[k * 16 + dg];
        a0 += h * w.x; a1 += h * w.y; a2 += h * w.z; a3 += h * w.w;
      }
      const int tg = t0 + it * 16 + tl;
      const size_t off = ((size_t)b * TT + tg) * 64 + dg * 4;
      float4 o; o.x = a0; o.y = a1; o.z = a2; o.w = a3;
      *(float4*)(out + off) = o;  // 16B-aligned fp32 store
    }
    __syncthreads();
  }
}

// ---------------------------------------------------------------------------
extern "C" void kernel_launch(void* const* d_in, const int* in_sizes, int n_in,
                              void* d_out, int out_size, void* d_ws, size_t ws_size,
                              hipStream_t stream) {
  const float* ts     = (const float*)d_in[0];
  const float* X      = (const float*)d_in[1];
  const float* M      = (const float*)d_in[2];
  const float* yts    = (const float*)d_in[3];
  const float* te_w   = (const float*)d_in[4];
  const float* te_b   = (const float*)d_in[5];
  const float* query  = (const float*)d_in[6];
  const float* qm_w   = (const float*)d_in[7];
  const float* qm_b   = (const float*)d_in[8];
  const float* km_w   = (const float*)d_in[9];
  const float* km_b   = (const float*)d_in[10];
  const float* out_w  = (const float*)d_in[11];
  const float* out_b  = (const float*)d_in[12];
  const float* dec_w1 = (const float*)d_in[13];
  const float* dec_b1 = (const float*)d_in[14];
  const float* dec_w2 = (const float*)d_in[15];
  const float* dec_b2 = (const float*)d_in[16];
  float* ws = (float*)d_ws;
  float* out = (float*)d_out;

  k1_prep<<<1, 256, 0, stream>>>(query, qm_w, qm_b, km_w, km_b, ws);
  k2_attn<<<dim3(LL / 128, BB), 256, 0, stream>>>(ts, X, M, te_w, te_b, ws);
  k3_coeffs<<<BB, 128, 0, stream>>>(out_w, out_b, dec_w1, dec_b1, ws, out);
  k4_decode<<<dim3(TT / 64, BB), 256, 0, stream>>>(yts, dec_w2, dec_b2, ws, out);
}

// Round 4
// 139.178 us; speedup vs baseline: 1.0262x; 1.0262x over previous
//
#include <hip/hip_runtime.h>
#include <hip/hip_bf16.h>

// Problem constants
#define BB 32
#define LL 2048
#define DD 64
#define TT 512
// H=2, P=2 -> hp index = h*2+p in [0,4)

// Workspace: partials [b][chunk][576] ; 576 = numer[4*64] denom[4*64] sumX[64]
#define NCHUNK 16
#define PSTRIDE 576

// ---------------------------------------------------------------------------
// k_attn: per block (chunk of 128 l's, batch b):
//   fold-in of query prep: q = query@qm_w + qm_b (LDS),
//     r[hp][i] = sum_e q[p][h*64+e]*km_w[i][h*64+e], c[hp] = q . km_b
//   scores -> exp -> masked weighted sums; partials stored (no atomics).
// grid (16, 32), block 256.
// ---------------------------------------------------------------------------
__global__ void __launch_bounds__(256) k_attn(
    const float* __restrict__ ts,
    const float* __restrict__ X,
    const float* __restrict__ M,
    const float* __restrict__ te_w,
    const float* __restrict__ te_b,
    const float* __restrict__ query,
    const float* __restrict__ qm_w,
    const float* __restrict__ qm_b,
    const float* __restrict__ km_w,
    const float* __restrict__ km_b,
    float* __restrict__ ws) {
  __shared__ float q_lds[256];
  __shared__ float r_lds[512], c_lds[4];
  __shared__ float tew[128], teb[128];
  __shared__ float w_lds[128 * 4];
  __shared__ float red[256 * 18];
  const int t = threadIdx.x;
  const int b = blockIdx.y;
  const int lc = blockIdx.x * 128;

  if (t < 128) { tew[t] = te_w[t]; teb[t] = te_b[t]; }
  {  // q[p][e] (t = p*128+e)
    const int p = t >> 7, e = t & 127;
    float acc = qm_b[e];
#pragma unroll 8
    for (int i = 0; i < 128; ++i)
      acc += query[p * 128 + i] * qm_w[i * 128 + e];
    q_lds[t] = acc;
  }
  __syncthreads();

  for (int o = t; o < 512; o += 256) {  // r[hp][i]
    const int hp = o >> 7, i = o & 127;
    const int h = hp >> 1, p = hp & 1;
    const float4* km4 = (const float4*)(km_w + i * 128 + h * 64);
    const float* qp = &q_lds[p * 128 + h * 64];
    float acc = 0.f;
#pragma unroll
    for (int e4 = 0; e4 < 16; ++e4) {
      const float4 w = km4[e4];
      acc += qp[e4 * 4] * w.x + qp[e4 * 4 + 1] * w.y +
             qp[e4 * 4 + 2] * w.z + qp[e4 * 4 + 3] * w.w;
    }
    r_lds[o] = acc;
  }
  if (t < 4) {  // c[hp]
    const int h = t >> 1, p = t & 1;
    float acc = 0.f;
    for (int e = 0; e < 64; ++e)
      acc += q_lds[p * 128 + h * 64 + e] * km_b[h * 64 + e];
    c_lds[t] = acc;
  }
  __syncthreads();

  {  // scores: 2 threads per l, each does 2 of the 4 hp dot-products
    const int ll = t >> 1, pair = t & 1;
    const float tt = ts[(size_t)b * LL + lc + ll];
    float a0 = 0.f, a1 = 0.f;
    const float* r0 = &r_lds[(pair * 2) * 128];
    const float* r1 = &r_lds[(pair * 2 + 1) * 128];
    for (int i = 0; i < 128; i += 2) {
      const float f0 = __sinf(tt * tew[i] + teb[i]);      // even idx: sin
      const float f1 = tt * tew[i + 1] + teb[i + 1];      // odd idx: identity
      a0 += f0 * r0[i] + f1 * r0[i + 1];
      a1 += f0 * r1[i] + f1 * r1[i + 1];
    }
    // scores are O(0.3): exp without max-subtraction is exact-safe and
    // softmax is shift-invariant, so this matches the reference.
    w_lds[ll * 4 + pair * 2]     = __expf((a0 + c_lds[pair * 2]) * 0.125f);
    w_lds[ll * 4 + pair * 2 + 1] = __expf((a1 + c_lds[pair * 2 + 1]) * 0.125f);
  }
  __syncthreads();

  // accumulate: thread -> (lr = t>>5 row group of 8, dpair = t&31 -> d=2*dpair)
  const int dpair = t & 31, lr = t >> 5;
  float n[4][2] = {}, dn[4][2] = {}, sx[2] = {};
  const float2* X2 = (const float2*)X;
  const float2* M2 = (const float2*)M;
  const size_t base = ((size_t)b * LL + lc) * 32;  // float2 units per row = 32
  for (int ll = lr; ll < 128; ll += 8) {
    const float2 xv = X2[base + (size_t)ll * 32 + dpair];
    const float2 mv = M2[base + (size_t)ll * 32 + dpair];
    const float mx0 = mv.x * xv.x, mx1 = mv.y * xv.y;
    sx[0] += xv.x; sx[1] += xv.y;
#pragma unroll
    for (int hp = 0; hp < 4; ++hp) {
      const float w = w_lds[ll * 4 + hp];
      n[hp][0]  += w * mx0;  n[hp][1]  += w * mx1;
      dn[hp][0] += w * mv.x; dn[hp][1] += w * mv.y;
    }
  }

#pragma unroll
  for (int hp = 0; hp < 4; ++hp) {
    red[t * 18 + hp * 2 + 0] = n[hp][0];
    red[t * 18 + hp * 2 + 1] = n[hp][1];
    red[t * 18 + 8 + hp * 2 + 0] = dn[hp][0];
    red[t * 18 + 8 + hp * 2 + 1] = dn[hp][1];
  }
  red[t * 18 + 16] = sx[0];
  red[t * 18 + 17] = sx[1];
  __syncthreads();

  if (t < 32) {
    float* slot = ws + ((size_t)b * NCHUNK + blockIdx.x) * PSTRIDE;
    for (int j = 0; j < 18; ++j) {
      float s = 0.f;
#pragma unroll
      for (int r2 = 0; r2 < 8; ++r2) s += red[(r2 * 32 + t) * 18 + j];
      if (j < 8) {
        const int hp = j >> 1, half = j & 1;
        slot[hp * 64 + 2 * t + half] = s;
      } else if (j < 16) {
        const int j2 = j - 8, hp = j2 >> 1, half = j2 & 1;
        slot[256 + hp * 64 + 2 * t + half] = s;
      } else {
        slot[512 + 2 * t + (j - 16)] = s;
      }
    }
  }
}

// ---------------------------------------------------------------------------
// k_dec: per block (64-t chunk, batch b):
//   reduce 16 partial slots -> x -> coeffs -> A,B (replicated per block),
//   then decode: h1 = relu(A + y*B); out = h1 @ dec_w2 + dec_b2.
//   Block x==0 also writes the coeffs output.
// grid (8, 32), block 256.
// ---------------------------------------------------------------------------
__global__ void __launch_bounds__(256) k_dec(
    const float* __restrict__ yts,
    const float* __restrict__ out_w,
    const float* __restrict__ out_b,
    const float* __restrict__ dec_w1,
    const float* __restrict__ dec_b1,
    const float* __restrict__ dec_w2,
    const float* __restrict__ dec_b2,
    const float* __restrict__ ws,
    float* __restrict__ out) {
  __shared__ float acc_l[576];
  __shared__ float x_lds[512];   // [p][h*128 + dd]
  __shared__ float c_lds[128];   // coeffs [p][j]
  __shared__ float ABl[128];     // A[k] at 0..63, B[k] at 64..127
  __shared__ __align__(16) float w2l[4096];  // dec_w2 [k*64+d]
  __shared__ float h1l[16 * 64];
  __shared__ float b2l[64], yl[64];
  const int t = threadIdx.x;
  const int b = blockIdx.y;
  const int t0 = blockIdx.x * 64;

  for (int i = t; i < 4096; i += 256) w2l[i] = dec_w2[i];
  {  // reduce the 16 chunk partials for this b
    const float* p = ws + (size_t)b * NCHUNK * PSTRIDE;
    for (int o = t; o < 576; o += 256) {
      float s = 0.f;
#pragma unroll
      for (int c = 0; c < NCHUNK; ++c) s += p[c * PSTRIDE + o];
      acc_l[o] = s;
    }
  }
  if (t < 64) { b2l[t] = dec_b2[t]; yl[t] = yts[b * TT + t0 + t]; }
  __syncthreads();

  {  // finalize x (t = hp*64+d); second half of value == mask -> x==1
    const int hp = t >> 6, d = t & 63;
    const int h = hp >> 1, p = hp & 1;
    const float num = acc_l[hp * 64 + d];
    const float den = acc_l[256 + hp * 64 + d];
    const float sxv = acc_l[512 + d];
    float x1, x2;
    if (den > 0.f) { x1 = num / den; x2 = 1.f; }
    else           { x1 = sxv * (1.f / (float)LL); x2 = 0.f; }  // uniform fallback
    x_lds[p * 256 + h * 128 + d] = x1;
    x_lds[p * 256 + h * 128 + 64 + d] = x2;
  }
  __syncthreads();

  if (t < 128) {  // coeffs[p][j]
    const int p = t >> 6, j = t & 63;
    float acc = out_b[j];
    for (int k = 0; k < 256; ++k)
      acc += x_lds[p * 256 + k] * out_w[k * 64 + j];
    c_lds[t] = acc;
    if (blockIdx.x == 0)
      out[(size_t)BB * TT * DD + b * 128 + t] = acc;  // fp32 coeffs output
  }
  __syncthreads();

  if (t < 64) {  // A[k], B[k]
    const int k = t;
    float a = dec_b1[k], bb = 0.f;
    for (int j = 0; j < 64; ++j) {
      const float w1 = dec_w1[j * 64 + k];
      a  += c_lds[j] * w1;
      bb += c_lds[64 + j] * w1;
    }
    ABl[k] = a;
    ABl[64 + k] = bb;
  }
  __syncthreads();

  const int tl = t >> 4, dg = t & 15;  // 16 t's x 16 d-groups(4 d each)
  for (int it = 0; it < 4; ++it) {
    {  // phase A: h1 for 16 t's (1024 values, 4 per thread)
      int idx = t;
#pragma unroll
      for (int rr = 0; rr < 4; ++rr, idx += 256) {
        const int tl2 = idx >> 6, k = idx & 63;
        h1l[idx] = fmaxf(ABl[k] + yl[it * 16 + tl2] * ABl[64 + k], 0.f);
      }
    }
    __syncthreads();
    {  // phase B: out tile
      float a0 = b2l[dg * 4], a1 = b2l[dg * 4 + 1],
            a2 = b2l[dg * 4 + 2], a3 = b2l[dg * 4 + 3];
      const float4* w4 = (const float4*)w2l;
      const float* h1p = &h1l[tl * 64];
      for (int k = 0; k < 64; ++k) {
        const float h = h1p[k];
        const float4 w = w4[k * 16 + dg];
        a0 += h * w.x; a1 += h * w.y; a2 += h * w.z; a3 += h * w.w;
      }
      const int tg = t0 + it * 16 + tl;
      const size_t off = ((size_t)b * TT + tg) * 64 + dg * 4;
      float4 o; o.x = a0; o.y = a1; o.z = a2; o.w = a3;
      *(float4*)(out + off) = o;  // 16B-aligned fp32 store
    }
    __syncthreads();
  }
}

// ---------------------------------------------------------------------------
extern "C" void kernel_launch(void* const* d_in, const int* in_sizes, int n_in,
                              void* d_out, int out_size, void* d_ws, size_t ws_size,
                              hipStream_t stream) {
  const float* ts     = (const float*)d_in[0];
  const float* X      = (const float*)d_in[1];
  const float* M      = (const float*)d_in[2];
  const float* yts    = (const float*)d_in[3];
  const float* te_w   = (const float*)d_in[4];
  const float* te_b   = (const float*)d_in[5];
  const float* query  = (const float*)d_in[6];
  const float* qm_w   = (const float*)d_in[7];
  const float* qm_b   = (const float*)d_in[8];
  const float* km_w   = (const float*)d_in[9];
  const float* km_b   = (const float*)d_in[10];
  const float* out_w  = (const float*)d_in[11];
  const float* out_b  = (const float*)d_in[12];
  const float* dec_w1 = (const float*)d_in[13];
  const float* dec_b1 = (const float*)d_in[14];
  const float* dec_w2 = (const float*)d_in[15];
  const float* dec_b2 = (const float*)d_in[16];
  float* ws = (float*)d_ws;
  float* out = (float*)d_out;

  k_attn<<<dim3(NCHUNK, BB), 256, 0, stream>>>(
      ts, X, M, te_w, te_b, query, qm_w, qm_b, km_w, km_b, ws);
  k_dec<<<dim3(TT / 64, BB), 256, 0, stream>>>(
      yts, out_w, out_b, dec_w1, dec_b1, dec_w2, dec_b2, ws, out);
}

// Round 5
// 134.612 us; speedup vs baseline: 1.0610x; 1.0339x over previous
//
#include <hip/hip_runtime.h>
#include <hip/hip_bf16.h>

// Problem constants
#define BB 32
#define LL 2048
#define DD 64
#define TT 512
#define INV2PI 0.15915494309189535f
// H=2, P=2 -> hp index = h*2+p in [0,4)

// Workspace: partials [b][chunk][576] ; 576 = numer[4*64] denom[4*64] sumX[64]
#define NCHUNK 16
#define PSTRIDE 576

// ---------------------------------------------------------------------------
// k_attn: per block (chunk of 128 l's, batch b):
//   q = query@qm_w + qm_b ; r[hp][i] = q . km_w cols ; odd-index (linear)
//   features folded to closed form t*C1+C0 ; even-index sin terms via
//   v_sin_f32 on prescaled revolutions. Then exp -> masked weighted sums.
// grid (16, 32), block 256.
// ---------------------------------------------------------------------------
__global__ void __launch_bounds__(256) k_attn(
    const float* __restrict__ ts,
    const float* __restrict__ X,
    const float* __restrict__ M,
    const float* __restrict__ te_w,
    const float* __restrict__ te_b,
    const float* __restrict__ query,
    const float* __restrict__ qm_w,
    const float* __restrict__ qm_b,
    const float* __restrict__ km_w,
    const float* __restrict__ km_b,
    float* __restrict__ ws) {
  __shared__ float q_lds[256];
  __shared__ float r_lds[512];               // [hp][i]
  __shared__ __align__(16) float rp4[256];   // [e][hp], e = even-i/2 < 64
  __shared__ __align__(8)  float feat2[128]; // [e][2] = (w_rev, b_rev)
  __shared__ float tsl[128];
  __shared__ float C0[4], C1[4];
  __shared__ float sred[1024];               // [t][hp] score partials
  __shared__ float w_lds[512];               // [l][hp]
  __shared__ float red[256 * 18];
  const int t = threadIdx.x;
  const int b = blockIdx.y;
  const int lc = blockIdx.x * 128;

  if (t < 128) tsl[t] = ts[(size_t)b * LL + lc + t];
  if (t < 64) {  // prescale even-index sin params to revolutions
    feat2[2 * t]     = te_w[2 * t] * INV2PI;
    feat2[2 * t + 1] = te_b[2 * t] * INV2PI;
  }

  {  // q[p][e] (t = p*128+e), 4 independent accumulators
    const int p = t >> 7, e = t & 127;
    const float* qq = query + p * 128;
    const float* qw = qm_w + e;
    float a0 = 0.f, a1 = 0.f, a2 = 0.f, a3 = 0.f;
    for (int i = 0; i < 128; i += 4) {
      a0 += qq[i]     * qw[i * 128];
      a1 += qq[i + 1] * qw[(i + 1) * 128];
      a2 += qq[i + 2] * qw[(i + 2) * 128];
      a3 += qq[i + 3] * qw[(i + 3) * 128];
    }
    q_lds[t] = (a0 + a1) + (a2 + a3) + qm_b[e];
  }

  // prefetch first half of this block's X/M rows into registers
  // (register loads don't drain at barriers; overlap HBM with prep/score)
  const int dpair = t & 31, lr = t >> 5;
  const float2* X2 = (const float2*)X;
  const float2* M2 = (const float2*)M;
  const size_t base = ((size_t)b * LL + lc) * 32;  // float2 units per row
  float2 xa[8], ma[8];
#pragma unroll
  for (int i = 0; i < 8; ++i) {
    xa[i] = X2[base + (size_t)(lr + i * 8) * 32 + dpair];
    ma[i] = M2[base + (size_t)(lr + i * 8) * 32 + dpair];
  }
  __syncthreads();

  for (int o = t; o < 512; o += 256) {  // r[hp][i]
    const int hp = o >> 7, i = o & 127;
    const int h = hp >> 1, p = hp & 1;
    const float4* km4 = (const float4*)(km_w + i * 128 + h * 64);
    const float* qp = &q_lds[p * 128 + h * 64];
    float acc = 0.f;
#pragma unroll
    for (int e4 = 0; e4 < 16; ++e4) {
      const float4 w = km4[e4];
      acc += qp[4 * e4] * w.x + qp[4 * e4 + 1] * w.y +
             qp[4 * e4 + 2] * w.z + qp[4 * e4 + 3] * w.w;
    }
    r_lds[o] = acc;
  }
  __syncthreads();

  if (t < 64) {  // pack r for the sin loop: rp4[e][hp] = r[hp][2e]
#pragma unroll
    for (int hp = 0; hp < 4; ++hp) rp4[t * 4 + hp] = r_lds[hp * 128 + 2 * t];
  }
  if (t >= 64 && t < 72) {  // closed-form odd terms: C1 = U, C0 = V + c
    const int hp = (t - 64) >> 1;
    if ((t & 1) == 0) {
      float s = 0.f;
      for (int e = 0; e < 64; ++e) s += te_w[2 * e + 1] * r_lds[hp * 128 + 2 * e + 1];
      C1[hp] = s;
    } else {
      float s = 0.f;
      for (int e = 0; e < 64; ++e) s += te_b[2 * e + 1] * r_lds[hp * 128 + 2 * e + 1];
      const int h = hp >> 1, p = hp & 1;
      float c = 0.f;
      for (int e = 0; e < 64; ++e) c += q_lds[p * 128 + h * 64 + e] * km_b[h * 64 + e];
      C0[hp] = s + c;
    }
  }
  __syncthreads();

  {  // sin partials: 2 threads/l, each 32 of the 64 even terms, all 4 hp
    const int l = t >> 1, half = t & 1;
    const float tt = tsl[l];
    const float2* f2 = (const float2*)feat2;
    const float4* r4 = (const float4*)rp4;
    float p0 = 0.f, p1 = 0.f, p2 = 0.f, p3 = 0.f;
    const int e0 = half * 32;
    for (int e = e0; e < e0 + 32; ++e) {
      const float2 wb = f2[e];
      const float f = __builtin_amdgcn_sinf(tt * wb.x + wb.y);  // sin(t*w+b)
      const float4 r = r4[e];
      p0 += f * r.x; p1 += f * r.y; p2 += f * r.z; p3 += f * r.w;
    }
    sred[t * 4 + 0] = p0; sred[t * 4 + 1] = p1;
    sred[t * 4 + 2] = p2; sred[t * 4 + 3] = p3;
  }
  __syncthreads();
  {  // combine + exp -> w_lds (scores O(0.3): no max-subtraction needed;
     // softmax is shift-invariant so this matches the reference)
    const int l = t >> 1, pr = t & 1;
    const float tt = tsl[l];
#pragma unroll
    for (int k2 = 0; k2 < 2; ++k2) {
      const int hp = pr * 2 + k2;
      const float s = sred[(2 * l) * 4 + hp] + sred[(2 * l + 1) * 4 + hp] +
                      tt * C1[hp] + C0[hp];
      w_lds[l * 4 + hp] = __expf(s * 0.125f);
    }
  }
  __syncthreads();

  // accumulate: lr row-group of 8, dpair -> d = 2*dpair
  float n[4][2] = {}, dn[4][2] = {}, sx[2] = {};
#pragma unroll
  for (int i = 0; i < 8; ++i) {  // prefetched half
    const int ll = lr + i * 8;
    const float2 xv = xa[i], mv = ma[i];
    const float mx0 = mv.x * xv.x, mx1 = mv.y * xv.y;
    sx[0] += xv.x; sx[1] += xv.y;
#pragma unroll
    for (int hp = 0; hp < 4; ++hp) {
      const float w = w_lds[ll * 4 + hp];
      n[hp][0]  += w * mx0;  n[hp][1]  += w * mx1;
      dn[hp][0] += w * mv.x; dn[hp][1] += w * mv.y;
    }
  }
  for (int i = 8; i < 16; ++i) {  // streamed half
    const int ll = lr + i * 8;
    const float2 xv = X2[base + (size_t)ll * 32 + dpair];
    const float2 mv = M2[base + (size_t)ll * 32 + dpair];
    const float mx0 = mv.x * xv.x, mx1 = mv.y * xv.y;
    sx[0] += xv.x; sx[1] += xv.y;
#pragma unroll
    for (int hp = 0; hp < 4; ++hp) {
      const float w = w_lds[ll * 4 + hp];
      n[hp][0]  += w * mx0;  n[hp][1]  += w * mx1;
      dn[hp][0] += w * mv.x; dn[hp][1] += w * mv.y;
    }
  }

#pragma unroll
  for (int hp = 0; hp < 4; ++hp) {
    red[t * 18 + hp * 2 + 0] = n[hp][0];
    red[t * 18 + hp * 2 + 1] = n[hp][1];
    red[t * 18 + 8 + hp * 2 + 0] = dn[hp][0];
    red[t * 18 + 8 + hp * 2 + 1] = dn[hp][1];
  }
  red[t * 18 + 16] = sx[0];
  red[t * 18 + 17] = sx[1];
  __syncthreads();

  if (t < 32) {
    float* slot = ws + ((size_t)b * NCHUNK + blockIdx.x) * PSTRIDE;
    for (int j = 0; j < 18; ++j) {
      float s = 0.f;
#pragma unroll
      for (int r2 = 0; r2 < 8; ++r2) s += red[(r2 * 32 + t) * 18 + j];
      if (j < 8) {
        const int hp = j >> 1, half = j & 1;
        slot[hp * 64 + 2 * t + half] = s;
      } else if (j < 16) {
        const int j2 = j - 8, hp = j2 >> 1, half = j2 & 1;
        slot[256 + hp * 64 + 2 * t + half] = s;
      } else {
        slot[512 + 2 * t + (j - 16)] = s;
      }
    }
  }
}

// ---------------------------------------------------------------------------
// k_dec: reduce 16 partial slots -> x -> coeffs (split-k over 256 thr) ->
// A,B (split-j over 128 thr) -> decode h1=relu(A+yB), out = h1@w2 + b2.
// Block x==0 writes the coeffs output. grid (8, 32), block 256.
// ---------------------------------------------------------------------------
__global__ void __launch_bounds__(256) k_dec(
    const float* __restrict__ yts,
    const float* __restrict__ out_w,
    const float* __restrict__ out_b,
    const float* __restrict__ dec_w1,
    const float* __restrict__ dec_b1,
    const float* __restrict__ dec_w2,
    const float* __restrict__ dec_b2,
    const float* __restrict__ ws,
    float* __restrict__ out) {
  __shared__ __align__(16) float acc_l[576];
  __shared__ float x_lds[512];   // [p][h*128 + dd]
  __shared__ float cred[256];
  __shared__ float c_lds[128];   // coeffs [p][j]
  __shared__ float abred[256];
  __shared__ float ABl[128];     // A[k] 0..63, B[k] 64..127
  __shared__ __align__(16) float w2l[4096];
  __shared__ float h1l[1024];
  __shared__ float b2l[64], yl[64];
  const int t = threadIdx.x;
  const int b = blockIdx.y;
  const int t0 = blockIdx.x * 64;

  {  // stage dec_w2 (16 KB) via float4
    const float4* s4 = (const float4*)dec_w2;
    float4* d4 = (float4*)w2l;
    for (int i = t; i < 1024; i += 256) d4[i] = s4[i];
  }
  if (t < 144) {  // reduce 16 chunk partials, float4-wide (576 = 144*4)
    const float4* p4 = (const float4*)(ws + (size_t)b * NCHUNK * PSTRIDE);
    float4 s; s.x = s.y = s.z = s.w = 0.f;
    for (int c = 0; c < NCHUNK; ++c) {
      const float4 v = p4[(size_t)c * 144 + t];
      s.x += v.x; s.y += v.y; s.z += v.z; s.w += v.w;
    }
    ((float4*)acc_l)[t] = s;
  }
  if (t >= 192) {
    const int k = t - 192;
    b2l[k] = dec_b2[k];
    yl[k] = yts[b * TT + t0 + k];
  }
  __syncthreads();

  {  // finalize x (t = hp*64+d); second half of value == mask -> x==1
    const int hp = t >> 6, d = t & 63;
    const int h = hp >> 1, p = hp & 1;
    const float num = acc_l[hp * 64 + d];
    const float den = acc_l[256 + hp * 64 + d];
    const float sxv = acc_l[512 + d];
    float x1, x2;
    if (den > 0.f) { x1 = num / den; x2 = 1.f; }
    else           { x1 = sxv * (1.f / (float)LL); x2 = 0.f; }  // uniform fallback
    x_lds[p * 256 + h * 128 + d] = x1;
    x_lds[p * 256 + h * 128 + 64 + d] = x2;
  }
  __syncthreads();

  {  // coeffs split-k: t = kh*128 + p*64 + j
    const int kh = t >> 7, pj = t & 127, p = pj >> 6, j = pj & 63;
    float acc = (kh == 0) ? out_b[j] : 0.f;
    const float* xp = &x_lds[p * 256 + kh * 128];
    const float* wp = out_w + (size_t)kh * 128 * 64 + j;
    for (int k = 0; k < 128; ++k) acc += xp[k] * wp[k * 64];
    cred[t] = acc;
  }
  __syncthreads();
  if (t < 128) {
    const float c = cred[t] + cred[t + 128];
    c_lds[t] = c;
    if (blockIdx.x == 0)
      out[(size_t)BB * TT * DD + b * 128 + t] = c;  // fp32 coeffs output
  }
  __syncthreads();
  if (t < 128) {  // A,B split-j: t = jh*64 + k
    const int jh = t >> 6, k = t & 63;
    float a = 0.f, bb = 0.f;
    const float* cp = &c_lds[jh * 32];
    const float* cp2 = &c_lds[64 + jh * 32];
    for (int j = 0; j < 32; ++j) {
      const float w1 = dec_w1[(jh * 32 + j) * 64 + k];
      a += cp[j] * w1;
      bb += cp2[j] * w1;
    }
    abred[t * 2] = a;
    abred[t * 2 + 1] = bb;
  }
  __syncthreads();
  if (t < 64) {
    ABl[t]      = dec_b1[t] + abred[t * 2]     + abred[(64 + t) * 2];
    ABl[64 + t] =             abred[t * 2 + 1] + abred[(64 + t) * 2 + 1];
  }
  __syncthreads();

  const int tl = t >> 4, dg = t & 15;  // 16 t's x 16 d-groups(4 d each)
  for (int it = 0; it < 4; ++it) {
    {  // phase A: h1 for 16 t's (1024 values, 4 per thread)
      int idx = t;
#pragma unroll
      for (int rr = 0; rr < 4; ++rr, idx += 256) {
        const int tl2 = idx >> 6, k = idx & 63;
        h1l[idx] = fmaxf(ABl[k] + yl[it * 16 + tl2] * ABl[64 + k], 0.f);
      }
    }
    __syncthreads();
    {  // phase B: out tile
      float a0 = b2l[dg * 4], a1 = b2l[dg * 4 + 1],
            a2 = b2l[dg * 4 + 2], a3 = b2l[dg * 4 + 3];
      const float4* w4 = (const float4*)w2l;
      const float* h1p = &h1l[tl * 64];
      for (int k = 0; k < 64; ++k) {
        const float h = h1p[k];
        const float4 w = w4[k * 16 + dg];
        a0 += h * w.x; a1 += h * w.y; a2 += h * w.z; a3 += h * w.w;
      }
      const int tg = t0 + it * 16 + tl;
      const size_t off = ((size_t)b * TT + tg) * 64 + dg * 4;
      float4 o; o.x = a0; o.y = a1; o.z = a2; o.w = a3;
      *(float4*)(out + off) = o;
    }
    __syncthreads();
  }
}

// ---------------------------------------------------------------------------
extern "C" void kernel_launch(void* const* d_in, const int* in_sizes, int n_in,
                              void* d_out, int out_size, void* d_ws, size_t ws_size,
                              hipStream_t stream) {
  const float* ts     = (const float*)d_in[0];
  const float* X      = (const float*)d_in[1];
  const float* M      = (const float*)d_in[2];
  const float* yts    = (const float*)d_in[3];
  const float* te_w   = (const float*)d_in[4];
  const float* te_b   = (const float*)d_in[5];
  const float* query  = (const float*)d_in[6];
  const float* qm_w   = (const float*)d_in[7];
  const float* qm_b   = (const float*)d_in[8];
  const float* km_w   = (const float*)d_in[9];
  const float* km_b   = (const float*)d_in[10];
  const float* out_w  = (const float*)d_in[11];
  const float* out_b  = (const float*)d_in[12];
  const float* dec_w1 = (const float*)d_in[13];
  const float* dec_b1 = (const float*)d_in[14];
  const float* dec_w2 = (const float*)d_in[15];
  const float* dec_b2 = (const float*)d_in[16];
  float* ws = (float*)d_ws;
  float* out = (float*)d_out;

  k_attn<<<dim3(NCHUNK, BB), 256, 0, stream>>>(
      ts, X, M, te_w, te_b, query, qm_w, qm_b, km_w, km_b, ws);
  k_dec<<<dim3(TT / 64, BB), 256, 0, stream>>>(
      yts, out_w, out_b, dec_w1, dec_b1, dec_w2, dec_b2, ws, out);
}